// Round 1
// baseline (35080.322 us; speedup 1.0000x reference)
//
#include <hip/hip_runtime.h>
#include <hip/hip_bf16.h>
#include <cstdint>

#define B_ 4
#define T_ 1024
#define E_ 1024
#define H_ 16
#define HS_ 64
#define L_ 8
#define F_DIM 4096
#define V_ 50257

__device__ inline float wave_sum(float v) {
#pragma unroll
  for (int off = 32; off > 0; off >>= 1) v += __shfl_down(v, off);
  return v;
}

// ---------------- embed: x[b,t,:] = tok_emb[idx[b,t],:] + pos_emb[t,:] --------
__global__ __launch_bounds__(256) void embed_kernel(
    const int* __restrict__ idx, const float* __restrict__ tok,
    const float* __restrict__ pos, float* __restrict__ x) {
  int bt = blockIdx.x;
  int t = bt & (T_ - 1);
  int tid = threadIdx.x;
  int tokid = idx[bt];
  float4 a = reinterpret_cast<const float4*>(tok + (size_t)tokid * E_)[tid];
  float4 p = reinterpret_cast<const float4*>(pos + (size_t)t * E_)[tid];
  float4 r = make_float4(a.x + p.x, a.y + p.y, a.z + p.z, a.w + p.w);
  reinterpret_cast<float4*>(x + (size_t)bt * E_)[tid] = r;
}

// ---------------- layernorm over E=1024, one block per row -------------------
__global__ __launch_bounds__(256) void ln_kernel(
    const float* __restrict__ in, const float* __restrict__ g,
    const float* __restrict__ b, float* __restrict__ out) {
  int row = blockIdx.x;
  int tid = threadIdx.x;
  const float* xr = in + (size_t)row * E_;
  float4 v = reinterpret_cast<const float4*>(xr)[tid];
  float s = v.x + v.y + v.z + v.w;
  float q = v.x * v.x + v.y * v.y + v.z * v.z + v.w * v.w;
  s = wave_sum(s);
  q = wave_sum(q);
  __shared__ float ls[4], lq[4];
  int wid = tid >> 6;
  if ((tid & 63) == 0) { ls[wid] = s; lq[wid] = q; }
  __syncthreads();
  float st = ls[0] + ls[1] + ls[2] + ls[3];
  float qt = lq[0] + lq[1] + lq[2] + lq[3];
  float mu = st * (1.0f / E_);
  float var = qt * (1.0f / E_) - mu * mu;
  float inv = rsqrtf(var + 1e-5f);
  float4 gg = reinterpret_cast<const float4*>(g)[tid];
  float4 bb = reinterpret_cast<const float4*>(b)[tid];
  float4 o;
  o.x = (v.x - mu) * inv * gg.x + bb.x;
  o.y = (v.y - mu) * inv * gg.y + bb.y;
  o.z = (v.z - mu) * inv * gg.z + bb.z;
  o.w = (v.w - mu) * inv * gg.w + bb.w;
  reinterpret_cast<float4*>(out + (size_t)row * E_)[tid] = o;
}

// ---------------- fused QKV projection per head ------------------------------
// grid: (T/64, B*H).  Computes q,k,v [64 x 64] tiles for one head.
__global__ __launch_bounds__(256) void qkv_kernel(
    const float* __restrict__ hin, const float* __restrict__ wq_l,
    const float* __restrict__ wk_l, const float* __restrict__ wv_l,
    float* __restrict__ q, float* __restrict__ k, float* __restrict__ v) {
  int t0 = blockIdx.x * 64;
  int bh = blockIdx.y;
  int b = bh >> 4;
  int hh = bh & 15;

  __shared__ float Xs[64][36];
  __shared__ float Wqs[32][68];
  __shared__ float Wks[32][68];
  __shared__ float Wvs[32][68];

  int tid = threadIdx.x;
  int tx = tid & 15, ty = tid >> 4;

  const float* Arow = hin + ((size_t)b * T_ + t0) * E_;
  const float* wqh = wq_l + (size_t)hh * E_ * HS_;
  const float* wkh = wk_l + (size_t)hh * E_ * HS_;
  const float* wvh = wv_l + (size_t)hh * E_ * HS_;

  float aq[4][4] = {}, ak[4][4] = {}, av[4][4] = {};

  for (int e0 = 0; e0 < E_; e0 += 32) {
#pragma unroll
    for (int i = tid; i < 64 * 32; i += 256) {
      int r = i >> 5, c = i & 31;
      Xs[r][c] = Arow[(size_t)r * E_ + e0 + c];
    }
#pragma unroll
    for (int i = tid; i < 32 * 64; i += 256) {
      int e = i >> 6, d = i & 63;
      Wqs[e][d] = wqh[(size_t)(e0 + e) * HS_ + d];
      Wks[e][d] = wkh[(size_t)(e0 + e) * HS_ + d];
      Wvs[e][d] = wvh[(size_t)(e0 + e) * HS_ + d];
    }
    __syncthreads();
#pragma unroll
    for (int kk = 0; kk < 32; ++kk) {
      float a0 = Xs[ty * 4 + 0][kk];
      float a1 = Xs[ty * 4 + 1][kk];
      float a2 = Xs[ty * 4 + 2][kk];
      float a3 = Xs[ty * 4 + 3][kk];
      float bq0 = Wqs[kk][tx * 4 + 0], bq1 = Wqs[kk][tx * 4 + 1];
      float bq2 = Wqs[kk][tx * 4 + 2], bq3 = Wqs[kk][tx * 4 + 3];
      float bk0 = Wks[kk][tx * 4 + 0], bk1 = Wks[kk][tx * 4 + 1];
      float bk2 = Wks[kk][tx * 4 + 2], bk3 = Wks[kk][tx * 4 + 3];
      float bv0 = Wvs[kk][tx * 4 + 0], bv1 = Wvs[kk][tx * 4 + 1];
      float bv2 = Wvs[kk][tx * 4 + 2], bv3 = Wvs[kk][tx * 4 + 3];
      aq[0][0] += a0 * bq0; aq[0][1] += a0 * bq1; aq[0][2] += a0 * bq2; aq[0][3] += a0 * bq3;
      aq[1][0] += a1 * bq0; aq[1][1] += a1 * bq1; aq[1][2] += a1 * bq2; aq[1][3] += a1 * bq3;
      aq[2][0] += a2 * bq0; aq[2][1] += a2 * bq1; aq[2][2] += a2 * bq2; aq[2][3] += a2 * bq3;
      aq[3][0] += a3 * bq0; aq[3][1] += a3 * bq1; aq[3][2] += a3 * bq2; aq[3][3] += a3 * bq3;
      ak[0][0] += a0 * bk0; ak[0][1] += a0 * bk1; ak[0][2] += a0 * bk2; ak[0][3] += a0 * bk3;
      ak[1][0] += a1 * bk0; ak[1][1] += a1 * bk1; ak[1][2] += a1 * bk2; ak[1][3] += a1 * bk3;
      ak[2][0] += a2 * bk0; ak[2][1] += a2 * bk1; ak[2][2] += a2 * bk2; ak[2][3] += a2 * bk3;
      ak[3][0] += a3 * bk0; ak[3][1] += a3 * bk1; ak[3][2] += a3 * bk2; ak[3][3] += a3 * bk3;
      av[0][0] += a0 * bv0; av[0][1] += a0 * bv1; av[0][2] += a0 * bv2; av[0][3] += a0 * bv3;
      av[1][0] += a1 * bv0; av[1][1] += a1 * bv1; av[1][2] += a1 * bv2; av[1][3] += a1 * bv3;
      av[2][0] += a2 * bv0; av[2][1] += a2 * bv1; av[2][2] += a2 * bv2; av[2][3] += a2 * bv3;
      av[3][0] += a3 * bv0; av[3][1] += a3 * bv1; av[3][2] += a3 * bv2; av[3][3] += a3 * bv3;
    }
    __syncthreads();
  }

#pragma unroll
  for (int i = 0; i < 4; ++i) {
    int t = t0 + ty * 4 + i;
    size_t base = ((size_t)bh * T_ + t) * HS_ + tx * 4;
#pragma unroll
    for (int j = 0; j < 4; ++j) {
      q[base + j] = aq[i][j];
      k[base + j] = ak[i][j];
      v[base + j] = av[i][j];
    }
  }
}

// ---------------- causal attention, one block (1 wave) per (b,h,t) -----------
__global__ __launch_bounds__(64) void attn_kernel(
    const float* __restrict__ q, const float* __restrict__ k,
    const float* __restrict__ v, float* __restrict__ o) {
  int g = blockIdx.x;
  int bh = g >> 10;
  int t = g & (T_ - 1);
  int b = bh >> 4;
  int hh = bh & 15;
  int lane = threadIdx.x;

  __shared__ float sc[T_];
  __shared__ float qs[HS_];

  const float* qrow = q + ((size_t)bh * T_ + t) * HS_;
  qs[lane] = qrow[lane];
  __syncthreads();

  const float* kb = k + (size_t)bh * T_ * HS_;
  float lmax = -1e30f;
  for (int s = lane; s <= t; s += 64) {
    const float* kr = kb + (size_t)s * HS_;
    float d = 0.f;
#pragma unroll
    for (int e = 0; e < HS_; e += 4) {
      float4 kk4 = *reinterpret_cast<const float4*>(kr + e);
      d += qs[e] * kk4.x + qs[e + 1] * kk4.y + qs[e + 2] * kk4.z + qs[e + 3] * kk4.w;
    }
    d *= 0.125f;  // HS^-0.5
    sc[s] = d;
    lmax = fmaxf(lmax, d);
  }
#pragma unroll
  for (int off = 32; off > 0; off >>= 1) lmax = fmaxf(lmax, __shfl_down(lmax, off));
  lmax = __shfl(lmax, 0);
  __syncthreads();

  float lsum = 0.f;
  for (int s = lane; s <= t; s += 64) {
    float p = __expf(sc[s] - lmax);
    sc[s] = p;
    lsum += p;
  }
  lsum = wave_sum(lsum);
  lsum = __shfl(lsum, 0);
  float inv = 1.0f / lsum;
  __syncthreads();

  const float* vb = v + (size_t)bh * T_ * HS_;
  int d = lane;
  float a0 = 0.f, a1 = 0.f, a2 = 0.f, a3 = 0.f;
  int s = 0;
  for (; s + 4 <= t + 1; s += 4) {
    a0 += sc[s + 0] * vb[(size_t)(s + 0) * HS_ + d];
    a1 += sc[s + 1] * vb[(size_t)(s + 1) * HS_ + d];
    a2 += sc[s + 2] * vb[(size_t)(s + 2) * HS_ + d];
    a3 += sc[s + 3] * vb[(size_t)(s + 3) * HS_ + d];
  }
  for (; s <= t; ++s) a0 += sc[s] * vb[(size_t)s * HS_ + d];
  float acc = (a0 + a1) + (a2 + a3);
  o[((size_t)b * T_ + t) * E_ + hh * HS_ + d] = acc * inv;
}

// ---------------- generic strided-B fp32 GEMM, 64x64 tile --------------------
// C[m,n] (ldc) = A[m,:] (lda, row-major) dot B[:,n] (element (k,n) at
// Bm[k*sBk + n*sBn]) + bias[n]; flags: 1 = C += (residual), 2 = relu.
__global__ __launch_bounds__(256) void gemm_kernel(
    const float* __restrict__ A, int lda,
    const float* __restrict__ Bm, int sBk, int sBn,
    const float* __restrict__ bias,
    float* __restrict__ C, int ldc,
    int M, int N, int K, int flags) {
  __shared__ float As[64][33];
  __shared__ float Bs[32][68];
  int n0 = blockIdx.x * 64;
  int m0 = blockIdx.y * 64;
  int tid = threadIdx.x;
  int tx = tid & 15, ty = tid >> 4;
  float acc[4][4] = {};

  for (int k0 = 0; k0 < K; k0 += 32) {
#pragma unroll
    for (int i = tid; i < 64 * 32; i += 256) {
      int r = i >> 5, kk = i & 31;
      As[r][kk] = A[(size_t)(m0 + r) * lda + k0 + kk];
    }
#pragma unroll
    for (int i = tid; i < 32 * 64; i += 256) {
      int kk = i >> 6, nn = i & 63;
      int n = n0 + nn;
      Bs[kk][nn] = (n < N) ? Bm[(size_t)(k0 + kk) * sBk + (size_t)n * sBn] : 0.f;
    }
    __syncthreads();
#pragma unroll
    for (int kk = 0; kk < 32; ++kk) {
      float a0 = As[ty * 4 + 0][kk];
      float a1 = As[ty * 4 + 1][kk];
      float a2 = As[ty * 4 + 2][kk];
      float a3 = As[ty * 4 + 3][kk];
      float b0 = Bs[kk][tx * 4 + 0];
      float b1 = Bs[kk][tx * 4 + 1];
      float b2 = Bs[kk][tx * 4 + 2];
      float b3 = Bs[kk][tx * 4 + 3];
      acc[0][0] += a0 * b0; acc[0][1] += a0 * b1; acc[0][2] += a0 * b2; acc[0][3] += a0 * b3;
      acc[1][0] += a1 * b0; acc[1][1] += a1 * b1; acc[1][2] += a1 * b2; acc[1][3] += a1 * b3;
      acc[2][0] += a2 * b0; acc[2][1] += a2 * b1; acc[2][2] += a2 * b2; acc[2][3] += a2 * b3;
      acc[3][0] += a3 * b0; acc[3][1] += a3 * b1; acc[3][2] += a3 * b2; acc[3][3] += a3 * b3;
    }
    __syncthreads();
  }

#pragma unroll
  for (int i = 0; i < 4; ++i) {
    int m = m0 + ty * 4 + i;
#pragma unroll
    for (int j = 0; j < 4; ++j) {
      int n = n0 + tx * 4 + j;
      if (n < N) {
        float r = acc[i][j];
        if (bias) r += bias[n];
        if (flags & 1) r += C[(size_t)m * ldc + n];
        if (flags & 2) r = fmaxf(r, 0.f);
        C[(size_t)m * ldc + n] = r;
      }
    }
  }
}

extern "C" void kernel_launch(void* const* d_in, const int* in_sizes, int n_in,
                              void* d_out, int out_size, void* d_ws, size_t ws_size,
                              hipStream_t stream) {
  (void)in_sizes; (void)n_in; (void)out_size; (void)ws_size;
  const int* idx = (const int*)d_in[0];
  const float* tok_emb = (const float*)d_in[1];
  const float* pos_emb = (const float*)d_in[2];
  const float* wq = (const float*)d_in[3];
  const float* wk = (const float*)d_in[4];
  const float* wv = (const float*)d_in[5];
  const float* wo = (const float*)d_in[6];
  const float* bo = (const float*)d_in[7];
  const float* ln1g = (const float*)d_in[8];
  const float* ln1b = (const float*)d_in[9];
  const float* ln2g = (const float*)d_in[10];
  const float* ln2b = (const float*)d_in[11];
  const float* w1 = (const float*)d_in[12];
  const float* b1 = (const float*)d_in[13];
  const float* w2 = (const float*)d_in[14];
  const float* b2 = (const float*)d_in[15];
  const float* lnfg = (const float*)d_in[16];
  const float* lnfb = (const float*)d_in[17];
  float* out = (float*)d_out;
  float* ws = (float*)d_ws;

  const size_t NX = (size_t)B_ * T_ * E_;  // 4M floats
  float* x = ws;
  float* h = ws + NX;
  float* q = ws + 2 * NX;
  float* k = ws + 3 * NX;
  float* v = ws + 4 * NX;
  float* o = ws + 5 * NX;
  float* ff = ws + 6 * NX;  // B*T*F = 4*NX floats -> total 10*NX = 168 MB

  embed_kernel<<<B_ * T_, 256, 0, stream>>>(idx, tok_emb, pos_emb, x);

  for (int l = 0; l < L_; ++l) {
    ln_kernel<<<B_ * T_, 256, 0, stream>>>(x, ln1g + l * E_, ln1b + l * E_, h);
    qkv_kernel<<<dim3(T_ / 64, B_ * H_), 256, 0, stream>>>(
        h, wq + (size_t)l * H_ * E_ * HS_, wk + (size_t)l * H_ * E_ * HS_,
        wv + (size_t)l * H_ * E_ * HS_, q, k, v);
    attn_kernel<<<B_ * H_ * T_, 64, 0, stream>>>(q, k, v, o);
    // x += o @ wo[l] + bo[l]
    gemm_kernel<<<dim3(E_ / 64, (B_ * T_) / 64), 256, 0, stream>>>(
        o, E_, wo + (size_t)l * E_ * E_, E_, 1, bo + (size_t)l * E_, x, E_,
        B_ * T_, E_, E_, 1);
    ln_kernel<<<B_ * T_, 256, 0, stream>>>(x, ln2g + l * E_, ln2b + l * E_, h);
    // ff = relu(h @ w1[l] + b1[l])
    gemm_kernel<<<dim3(F_DIM / 64, (B_ * T_) / 64), 256, 0, stream>>>(
        h, E_, w1 + (size_t)l * E_ * F_DIM, F_DIM, 1, b1 + (size_t)l * F_DIM,
        ff, F_DIM, B_ * T_, F_DIM, E_, 2);
    // x += ff @ w2[l] + b2[l]
    gemm_kernel<<<dim3(E_ / 64, (B_ * T_) / 64), 256, 0, stream>>>(
        ff, F_DIM, w2 + (size_t)l * F_DIM * E_, E_, 1, b2 + (size_t)l * E_,
        x, E_, B_ * T_, E_, F_DIM, 1);
  }

  ln_kernel<<<B_ * T_, 256, 0, stream>>>(x, lnfg, lnfb, h);
  // logits = h @ tok_emb^T  (B element (k,n) = tok_emb[n*E + k])
  gemm_kernel<<<dim3((V_ + 63) / 64, (B_ * T_) / 64), 256, 0, stream>>>(
      h, E_, tok_emb, 1, E_, nullptr, out, V_, B_ * T_, V_, E_, 0);
}

// Round 2
// 11426.523 us; speedup vs baseline: 3.0701x; 3.0701x over previous
//
#include <hip/hip_runtime.h>
#include <cstdint>

#define B_ 4
#define T_ 1024
#define E_ 1024
#define H_ 16
#define HS_ 64
#define L_ 8
#define F_DIM 4096
#define V_ 50257
#define VP_ 50304  // V padded to multiple of 128

typedef __attribute__((ext_vector_type(8))) short bf16x8;
typedef __attribute__((ext_vector_type(4))) float f32x4;
typedef unsigned short u16;

__device__ inline float b2f(u16 u) {
  unsigned int v = ((unsigned int)u) << 16;
  return __builtin_bit_cast(float, v);
}
__device__ inline u16 f2b(float f) {
  unsigned int u = __builtin_bit_cast(unsigned int, f);
  unsigned int r = (u + 0x7FFFu + ((u >> 16) & 1u)) >> 16;
  return (u16)r;
}

__device__ inline float wave_sum(float v) {
#pragma unroll
  for (int off = 32; off > 0; off >>= 1) v += __shfl_down(v, off);
  return v;
}

#define GLOAD16(gp, lp)                                                        \
  __builtin_amdgcn_global_load_lds(                                            \
      (const __attribute__((address_space(1))) unsigned int*)(gp),             \
      (__attribute__((address_space(3))) unsigned int*)(lp), 16, 0, 0)

// ---------------- embed: x[b,t,:] = tok_emb[idx[b,t],:] + pos_emb[t,:] -------
__global__ __launch_bounds__(256) void embed_kernel(
    const int* __restrict__ idx, const float* __restrict__ tok,
    const float* __restrict__ pos, float* __restrict__ x) {
  int bt = blockIdx.x;
  int t = bt & (T_ - 1);
  int tid = threadIdx.x;
  int tokid = idx[bt];
  float4 a = reinterpret_cast<const float4*>(tok + (size_t)tokid * E_)[tid];
  float4 p = reinterpret_cast<const float4*>(pos + (size_t)t * E_)[tid];
  float4 r = make_float4(a.x + p.x, a.y + p.y, a.z + p.z, a.w + p.w);
  reinterpret_cast<float4*>(x + (size_t)bt * E_)[tid] = r;
}

// ---------------- layernorm fp32 -> bf16, one block per row ------------------
__global__ __launch_bounds__(256) void ln_kernel(
    const float* __restrict__ in, const float* __restrict__ g,
    const float* __restrict__ b, u16* __restrict__ out) {
  int row = blockIdx.x;
  int tid = threadIdx.x;
  const float* xr = in + (size_t)row * E_;
  float4 v = reinterpret_cast<const float4*>(xr)[tid];
  float s = v.x + v.y + v.z + v.w;
  float q = v.x * v.x + v.y * v.y + v.z * v.z + v.w * v.w;
  s = wave_sum(s);
  q = wave_sum(q);
  __shared__ float ls[4], lq[4];
  int wid = tid >> 6;
  if ((tid & 63) == 0) { ls[wid] = s; lq[wid] = q; }
  __syncthreads();
  float st = ls[0] + ls[1] + ls[2] + ls[3];
  float qt = lq[0] + lq[1] + lq[2] + lq[3];
  float mu = st * (1.0f / E_);
  float var = qt * (1.0f / E_) - mu * mu;
  float inv = rsqrtf(var + 1e-5f);
  float4 gg = reinterpret_cast<const float4*>(g)[tid];
  float4 bb = reinterpret_cast<const float4*>(b)[tid];
  ushort4 o4;
  o4.x = f2b((v.x - mu) * inv * gg.x + bb.x);
  o4.y = f2b((v.y - mu) * inv * gg.y + bb.y);
  o4.z = f2b((v.z - mu) * inv * gg.z + bb.z);
  o4.w = f2b((v.w - mu) * inv * gg.w + bb.w);
  reinterpret_cast<ushort4*>(out + (size_t)row * E_)[tid] = o4;
}

// ------------- transpose-convert: out[n][k] bf16 <- in[k][n] fp32 ------------
__global__ __launch_bounds__(256) void convT_kernel(
    const float* __restrict__ in, u16* __restrict__ out, int K, int N) {
  __shared__ float tile[64][65];
  int n0 = blockIdx.x * 64, k0 = blockIdx.y * 64;
  int tx = threadIdx.x & 63, ty = threadIdx.x >> 6;
#pragma unroll
  for (int r = 0; r < 64; r += 4)
    tile[r + ty][tx] = in[(size_t)(k0 + r + ty) * N + n0 + tx];
  __syncthreads();
#pragma unroll
  for (int r = 0; r < 64; r += 4)
    out[(size_t)(n0 + r + ty) * K + k0 + tx] = f2b(tile[tx][r + ty]);
}

// --- QKV weight gather: out[(src*1024 + h*64 + d)][e] <- w_src[h][e][d] ------
__global__ __launch_bounds__(256) void convQKV_kernel(
    const float* __restrict__ wq, const float* __restrict__ wk,
    const float* __restrict__ wv, u16* __restrict__ out) {
  int src = blockIdx.x >> 4, hh = blockIdx.x & 15, e0 = blockIdx.y * 64;
  const float* w =
      (src == 0 ? wq : (src == 1 ? wk : wv)) + (size_t)hh * E_ * HS_;
  __shared__ float tile[64][65];
  int tx = threadIdx.x & 63, ty = threadIdx.x >> 6;
#pragma unroll
  for (int r = 0; r < 64; r += 4)
    tile[r + ty][tx] = w[(size_t)(e0 + r + ty) * HS_ + tx];  // tile[e][d]
  __syncthreads();
  size_t nb = (size_t)src * 1024 + hh * 64;
#pragma unroll
  for (int r = 0; r < 64; r += 4)
    out[(nb + r + ty) * E_ + e0 + tx] = f2b(tile[tx][r + ty]);
}

// ---------------- tok_emb straight convert with zero-pad rows ----------------
__global__ __launch_bounds__(256) void convTok_kernel(
    const float* __restrict__ tok, u16* __restrict__ out) {
  int row = blockIdx.x;
  int tid = threadIdx.x;
  ushort4 o4;
  if (row < V_) {
    float4 v = reinterpret_cast<const float4*>(tok + (size_t)row * E_)[tid];
    o4.x = f2b(v.x); o4.y = f2b(v.y); o4.z = f2b(v.z); o4.w = f2b(v.w);
  } else {
    o4 = make_ushort4(0, 0, 0, 0);
  }
  reinterpret_cast<ushort4*>(out + (size_t)row * E_)[tid] = o4;
}

// ---------------- MFMA bf16 GEMM, 128x128 tile, m97 structure ----------------
// C[m,n] = sum_k A[m][k] * Bt[n][k]  (+bias, +resid, relu per flags)
// A: [M][lda] bf16 row-major-k.  Bt: [N][ldb] bf16 row-major-k.
// flags: 1 = Cf += (residual read from Cf), 2 = relu.  Cb!=null -> bf16 out.
__global__ __launch_bounds__(256) void mfma_gemm_kernel(
    const u16* __restrict__ A, int lda, const u16* __restrict__ Bt, int ldb,
    const float* __restrict__ bias, float* __restrict__ Cf,
    u16* __restrict__ Cb, int ldc, int N, int K, int flags) {
  __shared__ u16 As[128 * 32];
  __shared__ u16 Bs[128 * 32];
  int m0 = blockIdx.x * 128, n0 = blockIdx.y * 128;
  int tid = threadIdx.x;
  int wave = tid >> 6, lane = tid & 63;
  int wr = wave >> 1, wc = wave & 1;

  f32x4 acc[4][4];
#pragma unroll
  for (int i = 0; i < 4; ++i)
#pragma unroll
    for (int j = 0; j < 4; ++j) acc[i][j] = (f32x4){0.f, 0.f, 0.f, 0.f};

  // staging: 8 chunks of 16 rows x 32 k per tile; wave handles 2 chunks each
  int c0 = wave * 2, c1 = wave * 2 + 1;
  int sr0 = c0 * 16 + (lane >> 2), sr1 = c1 * 16 + (lane >> 2);
  int sc = (lane & 3) * 8;
  const u16* Ag0 = A + (size_t)(m0 + sr0) * lda + sc;
  const u16* Ag1 = A + (size_t)(m0 + sr1) * lda + sc;
  const u16* Bg0 = Bt + (size_t)(n0 + sr0) * ldb + sc;
  const u16* Bg1 = Bt + (size_t)(n0 + sr1) * ldb + sc;
  u16* lA0 = &As[c0 * 512];
  u16* lA1 = &As[c1 * 512];
  u16* lB0 = &Bs[c0 * 512];
  u16* lB1 = &Bs[c1 * 512];

  int lrow = lane & 15, loct = lane >> 4;
  const int arow0 = (wr * 64 + lrow) * 32 + loct * 8;
  const int brow0 = (wc * 64 + lrow) * 32 + loct * 8;

  for (int k0 = 0; k0 < K; k0 += 32) {
    GLOAD16(Ag0 + k0, lA0);
    GLOAD16(Ag1 + k0, lA1);
    GLOAD16(Bg0 + k0, lB0);
    GLOAD16(Bg1 + k0, lB1);
    __syncthreads();  // drains vmcnt -> tiles visible
    bf16x8 af[4], bfr[4];
#pragma unroll
    for (int mf = 0; mf < 4; ++mf)
      af[mf] = *(const bf16x8*)&As[arow0 + mf * 16 * 32];
#pragma unroll
    for (int nf = 0; nf < 4; ++nf)
      bfr[nf] = *(const bf16x8*)&Bs[brow0 + nf * 16 * 32];
#pragma unroll
    for (int mf = 0; mf < 4; ++mf)
#pragma unroll
      for (int nf = 0; nf < 4; ++nf)
        acc[mf][nf] = __builtin_amdgcn_mfma_f32_16x16x32_bf16(
            af[mf], bfr[nf], acc[mf][nf], 0, 0, 0);
    __syncthreads();  // all waves done reading before next overwrite
  }

  int lq = lane >> 4;
#pragma unroll
  for (int mf = 0; mf < 4; ++mf) {
#pragma unroll
    for (int nf = 0; nf < 4; ++nf) {
      int n = n0 + wc * 64 + nf * 16 + lrow;
      if (n < N) {
        float bv = bias ? bias[n] : 0.f;
#pragma unroll
        for (int j = 0; j < 4; ++j) {
          int m = m0 + wr * 64 + mf * 16 + lq * 4 + j;
          float r = acc[mf][nf][j] + bv;
          if (flags & 1) r += Cf[(size_t)m * ldc + n];
          if (flags & 2) r = fmaxf(r, 0.f);
          if (Cb)
            Cb[(size_t)m * ldc + n] = f2b(r);
          else
            Cf[(size_t)m * ldc + n] = r;
        }
      }
    }
  }
}

// ---------------- causal attention, one wave per (b,h,t), bf16 qkv -----------
// qkv: [B*T][3072] bf16, cols 0..1023=q(h*64+d), 1024..=k, 2048..=v
__global__ __launch_bounds__(64) void attn_kernel(
    const u16* __restrict__ qkv, u16* __restrict__ o) {
  int g = blockIdx.x;
  int t = g & (T_ - 1);
  int bh = g >> 10;
  int b = bh >> 4, hh = bh & 15;
  int lane = threadIdx.x;

  __shared__ float scb[T_];
  __shared__ float qs[HS_];

  const u16* base = qkv + (size_t)b * T_ * 3072 + hh * 64;
  const u16* qrow = base + (size_t)t * 3072;
  qs[lane] = b2f(qrow[lane]) * 0.125f;  // fold HS^-0.5 into q
  __syncthreads();

  const u16* kb = base + 1024;
  float lmax = -1e30f;
  for (int s = lane; s <= t; s += 64) {
    const u16* kr = kb + (size_t)s * 3072;
    float d = 0.f;
#pragma unroll
    for (int e = 0; e < 64; e += 8) {
      bf16x8 kk = *(const bf16x8*)(kr + e);
#pragma unroll
      for (int j = 0; j < 8; ++j) d += qs[e + j] * b2f((u16)kk[j]);
    }
    scb[s] = d;
    lmax = fmaxf(lmax, d);
  }
#pragma unroll
  for (int off = 32; off > 0; off >>= 1)
    lmax = fmaxf(lmax, __shfl_down(lmax, off));
  lmax = __shfl(lmax, 0);
  __syncthreads();

  float lsum = 0.f;
  for (int s = lane; s <= t; s += 64) {
    float p = __expf(scb[s] - lmax);
    scb[s] = p;
    lsum += p;
  }
  lsum = wave_sum(lsum);
  lsum = __shfl(lsum, 0);
  float inv = 1.0f / lsum;
  __syncthreads();

  const u16* vb = base + 2048;
  float a0 = 0.f, a1 = 0.f, a2 = 0.f, a3 = 0.f;
  int s = 0;
  for (; s + 4 <= t + 1; s += 4) {
    a0 += scb[s + 0] * b2f(vb[(size_t)(s + 0) * 3072 + lane]);
    a1 += scb[s + 1] * b2f(vb[(size_t)(s + 1) * 3072 + lane]);
    a2 += scb[s + 2] * b2f(vb[(size_t)(s + 2) * 3072 + lane]);
    a3 += scb[s + 3] * b2f(vb[(size_t)(s + 3) * 3072 + lane]);
  }
  for (; s <= t; ++s) a0 += scb[s] * b2f(vb[(size_t)s * 3072 + lane]);
  float acc = (a0 + a1) + (a2 + a3);
  o[(size_t)(b * T_ + t) * E_ + hh * 64 + lane] = f2b(acc * inv);
}

extern "C" void kernel_launch(void* const* d_in, const int* in_sizes, int n_in,
                              void* d_out, int out_size, void* d_ws,
                              size_t ws_size, hipStream_t stream) {
  (void)in_sizes; (void)n_in; (void)out_size; (void)ws_size;
  const int* idx = (const int*)d_in[0];
  const float* tok_emb = (const float*)d_in[1];
  const float* pos_emb = (const float*)d_in[2];
  const float* wq = (const float*)d_in[3];
  const float* wk = (const float*)d_in[4];
  const float* wv = (const float*)d_in[5];
  const float* wo = (const float*)d_in[6];
  const float* bo = (const float*)d_in[7];
  const float* ln1g = (const float*)d_in[8];
  const float* ln1b = (const float*)d_in[9];
  const float* ln2g = (const float*)d_in[10];
  const float* ln2b = (const float*)d_in[11];
  const float* w1 = (const float*)d_in[12];
  const float* b1 = (const float*)d_in[13];
  const float* w2 = (const float*)d_in[14];
  const float* b2 = (const float*)d_in[15];
  const float* lnfg = (const float*)d_in[16];
  const float* lnfb = (const float*)d_in[17];
  float* out = (float*)d_out;
  char* ws = (char*)d_ws;

  // ws layout (bytes); total 117,440,512 (<168MB proven safe)
  u16* h = (u16*)(ws + 0);                    //  8 MB  [4096][1024] bf16
  float* x = (float*)(ws + 8388608);          // 16 MB  [4096][1024] f32
  u16* qkvb = (u16*)(ws + 25165824);          // 24 MB  [4096][3072] bf16
  u16* ob = (u16*)(ws + 50331648);            //  8 MB  [4096][1024] bf16
  u16* ffb = (u16*)(ws + 58720256);           // 32 MB  [4096][4096] bf16
  u16* wqkvT = (u16*)(ws + 92274688);         //  6 MB  [3072][1024] bf16
  u16* woT = (u16*)(ws + 98566144);           //  2 MB  [1024][1024] bf16
  u16* w1T = (u16*)(ws + 100663296);          //  8 MB  [4096][1024] bf16
  u16* w2T = (u16*)(ws + 109051904);          //  8 MB  [1024][4096] bf16
  // tok_bf aliases [x ... w2T) — everything there is dead by logits time
  u16* tokb = (u16*)(ws + 8388608);           // 103 MB [50304][1024] bf16

  embed_kernel<<<B_ * T_, 256, 0, stream>>>(idx, tok_emb, pos_emb, x);

  for (int l = 0; l < L_; ++l) {
    ln_kernel<<<B_ * T_, 256, 0, stream>>>(x, ln1g + l * E_, ln1b + l * E_, h);
    convQKV_kernel<<<dim3(48, 16), 256, 0, stream>>>(
        wq + (size_t)l * H_ * E_ * HS_, wk + (size_t)l * H_ * E_ * HS_,
        wv + (size_t)l * H_ * E_ * HS_, wqkvT);
    // qkv = h @ Wqkv   [4096][3072] bf16
    mfma_gemm_kernel<<<dim3(32, 24), 256, 0, stream>>>(
        h, E_, wqkvT, E_, nullptr, nullptr, qkvb, 3072, 3072, E_, 0);
    attn_kernel<<<B_ * H_ * T_, 64, 0, stream>>>(qkvb, ob);
    convT_kernel<<<dim3(16, 16), 256, 0, stream>>>(
        wo + (size_t)l * E_ * E_, woT, E_, E_);
    // x += o @ wo + bo
    mfma_gemm_kernel<<<dim3(32, 8), 256, 0, stream>>>(
        ob, E_, woT, E_, bo + (size_t)l * E_, x, nullptr, E_, E_, E_, 1);
    ln_kernel<<<B_ * T_, 256, 0, stream>>>(x, ln2g + l * E_, ln2b + l * E_, h);
    convT_kernel<<<dim3(64, 16), 256, 0, stream>>>(
        w1 + (size_t)l * E_ * F_DIM, w1T, E_, F_DIM);
    // ff = relu(h @ w1 + b1)  [4096][4096] bf16
    mfma_gemm_kernel<<<dim3(32, 32), 256, 0, stream>>>(
        h, E_, w1T, E_, b1 + (size_t)l * F_DIM, nullptr, ffb, F_DIM, F_DIM,
        E_, 2);
    convT_kernel<<<dim3(16, 64), 256, 0, stream>>>(
        w2 + (size_t)l * F_DIM * E_, w2T, F_DIM, E_);
    // x += ff @ w2 + b2
    mfma_gemm_kernel<<<dim3(32, 8), 256, 0, stream>>>(
        ffb, F_DIM, w2T, F_DIM, b2 + (size_t)l * E_, x, nullptr, E_, E_,
        F_DIM, 1);
  }

  ln_kernel<<<B_ * T_, 256, 0, stream>>>(x, lnfg, lnfb, h);
  convTok_kernel<<<VP_, 256, 0, stream>>>(tok_emb, tokb);
  // logits = h @ tok_emb^T   [4096][50257] fp32
  mfma_gemm_kernel<<<dim3(32, VP_ / 128), 256, 0, stream>>>(
      h, E_, tokb, E_, nullptr, out, nullptr, V_, V_, E_, 0);
}

// Round 3
// 3640.628 us; speedup vs baseline: 9.6358x; 3.1386x over previous
//
#include <hip/hip_runtime.h>
#include <cstdint>

#define B_ 4
#define T_ 1024
#define E_ 1024
#define H_ 16
#define HS_ 64
#define L_ 8
#define F_DIM 4096
#define V_ 50257
#define VP_ 50304  // V padded to multiple of 128

typedef __attribute__((ext_vector_type(8))) short bf16x8;
typedef __attribute__((ext_vector_type(4))) float f32x4;
typedef unsigned short u16;

__device__ inline float b2f(u16 u) {
  unsigned int v = ((unsigned int)u) << 16;
  return __builtin_bit_cast(float, v);
}
__device__ inline u16 f2b(float f) {
  unsigned int u = __builtin_bit_cast(unsigned int, f);
  unsigned int r = (u + 0x7FFFu + ((u >> 16) & 1u)) >> 16;
  return (u16)r;
}

__device__ inline float wave_sum(float v) {
#pragma unroll
  for (int off = 32; off > 0; off >>= 1) v += __shfl_down(v, off);
  return v;
}

#define GLOAD16(gp, lp)                                                        \
  __builtin_amdgcn_global_load_lds(                                            \
      (const __attribute__((address_space(1))) unsigned int*)(gp),             \
      (__attribute__((address_space(3))) unsigned int*)(lp), 16, 0, 0)

// ---------------- embed: x[b,t,:] = tok_emb[idx[b,t],:] + pos_emb[t,:] -------
__global__ __launch_bounds__(256) void embed_kernel(
    const int* __restrict__ idx, const float* __restrict__ tok,
    const float* __restrict__ pos, float* __restrict__ x) {
  int bt = blockIdx.x;
  int t = bt & (T_ - 1);
  int tid = threadIdx.x;
  int tokid = idx[bt];
  float4 a = reinterpret_cast<const float4*>(tok + (size_t)tokid * E_)[tid];
  float4 p = reinterpret_cast<const float4*>(pos + (size_t)t * E_)[tid];
  float4 r = make_float4(a.x + p.x, a.y + p.y, a.z + p.z, a.w + p.w);
  reinterpret_cast<float4*>(x + (size_t)bt * E_)[tid] = r;
}

// ---------------- layernorm fp32 -> bf16, one block per row ------------------
__global__ __launch_bounds__(256) void ln_kernel(
    const float* __restrict__ in, const float* __restrict__ g,
    const float* __restrict__ b, u16* __restrict__ out) {
  int row = blockIdx.x;
  int tid = threadIdx.x;
  const float* xr = in + (size_t)row * E_;
  float4 v = reinterpret_cast<const float4*>(xr)[tid];
  float s = v.x + v.y + v.z + v.w;
  float q = v.x * v.x + v.y * v.y + v.z * v.z + v.w * v.w;
  s = wave_sum(s);
  q = wave_sum(q);
  __shared__ float ls[4], lq[4];
  int wid = tid >> 6;
  if ((tid & 63) == 0) { ls[wid] = s; lq[wid] = q; }
  __syncthreads();
  float st = ls[0] + ls[1] + ls[2] + ls[3];
  float qt = lq[0] + lq[1] + lq[2] + lq[3];
  float mu = st * (1.0f / E_);
  float var = qt * (1.0f / E_) - mu * mu;
  float inv = rsqrtf(var + 1e-5f);
  float4 gg = reinterpret_cast<const float4*>(g)[tid];
  float4 bb = reinterpret_cast<const float4*>(b)[tid];
  ushort4 o4;
  o4.x = f2b((v.x - mu) * inv * gg.x + bb.x);
  o4.y = f2b((v.y - mu) * inv * gg.y + bb.y);
  o4.z = f2b((v.z - mu) * inv * gg.z + bb.z);
  o4.w = f2b((v.w - mu) * inv * gg.w + bb.w);
  reinterpret_cast<ushort4*>(out + (size_t)row * E_)[tid] = o4;
}

// ------------- transpose-convert: out[n][k] bf16 <- in[k][n] fp32 ------------
__global__ __launch_bounds__(256) void convT_kernel(
    const float* __restrict__ in, u16* __restrict__ out, int K, int N) {
  __shared__ float tile[64][65];
  int n0 = blockIdx.x * 64, k0 = blockIdx.y * 64;
  int tx = threadIdx.x & 63, ty = threadIdx.x >> 6;
#pragma unroll
  for (int r = 0; r < 64; r += 4)
    tile[r + ty][tx] = in[(size_t)(k0 + r + ty) * N + n0 + tx];
  __syncthreads();
#pragma unroll
  for (int r = 0; r < 64; r += 4)
    out[(size_t)(n0 + r + ty) * K + k0 + tx] = f2b(tile[tx][r + ty]);
}

// --- QKV weight gather: out[(src*1024 + h*64 + d)][e] <- w_src[h][e][d] ------
__global__ __launch_bounds__(256) void convQKV_kernel(
    const float* __restrict__ wq, const float* __restrict__ wk,
    const float* __restrict__ wv, u16* __restrict__ out) {
  int src = blockIdx.x >> 4, hh = blockIdx.x & 15, e0 = blockIdx.y * 64;
  const float* w =
      (src == 0 ? wq : (src == 1 ? wk : wv)) + (size_t)hh * E_ * HS_;
  __shared__ float tile[64][65];
  int tx = threadIdx.x & 63, ty = threadIdx.x >> 6;
#pragma unroll
  for (int r = 0; r < 64; r += 4)
    tile[r + ty][tx] = w[(size_t)(e0 + r + ty) * HS_ + tx];  // tile[e][d]
  __syncthreads();
  size_t nb = (size_t)src * 1024 + hh * 64;
#pragma unroll
  for (int r = 0; r < 64; r += 4)
    out[(nb + r + ty) * E_ + e0 + tx] = f2b(tile[tx][r + ty]);
}

// ---------------- tok_emb straight convert with zero-pad rows ----------------
__global__ __launch_bounds__(256) void convTok_kernel(
    const float* __restrict__ tok, u16* __restrict__ out) {
  int row = blockIdx.x;
  int tid = threadIdx.x;
  ushort4 o4;
  if (row < V_) {
    float4 v = reinterpret_cast<const float4*>(tok + (size_t)row * E_)[tid];
    o4.x = f2b(v.x); o4.y = f2b(v.y); o4.z = f2b(v.z); o4.w = f2b(v.w);
  } else {
    o4 = make_ushort4(0, 0, 0, 0);
  }
  reinterpret_cast<ushort4*>(out + (size_t)row * E_)[tid] = o4;
}

// -------- V transpose: vt[bh][d][t] <- qkv[b*T+t][2048 + h*64 + d] -----------
__global__ __launch_bounds__(256) void vtrans_kernel(
    const u16* __restrict__ qkv, u16* __restrict__ vt) {
  int t0 = blockIdx.x * 64;
  int bh = blockIdx.y;
  int b = bh >> 4, hh = bh & 15;
  __shared__ unsigned int tile[64][65];
  int tx = threadIdx.x & 63, ty = threadIdx.x >> 6;
  const u16* src = qkv + ((size_t)(b * T_ + t0)) * 3072 + 2048 + hh * 64;
#pragma unroll
  for (int r = 0; r < 64; r += 4)
    tile[r + ty][tx] = src[(size_t)(r + ty) * 3072 + tx];  // tile[t][d]
  __syncthreads();
  u16* dst = vt + ((size_t)bh * 64) * 1024 + t0;
#pragma unroll
  for (int r = 0; r < 64; r += 4)
    dst[(size_t)(r + ty) * 1024 + tx] = (u16)tile[tx][r + ty];
}

// ---------------- MFMA bf16 GEMM, 128x128 tile, m97 structure ----------------
__global__ __launch_bounds__(256) void mfma_gemm_kernel(
    const u16* __restrict__ A, int lda, const u16* __restrict__ Bt, int ldb,
    const float* __restrict__ bias, float* __restrict__ Cf,
    u16* __restrict__ Cb, int ldc, int N, int K, int flags) {
  __shared__ u16 As[128 * 32];
  __shared__ u16 Bs[128 * 32];
  int m0 = blockIdx.x * 128, n0 = blockIdx.y * 128;
  int tid = threadIdx.x;
  int wave = tid >> 6, lane = tid & 63;
  int wr = wave >> 1, wc = wave & 1;

  f32x4 acc[4][4];
#pragma unroll
  for (int i = 0; i < 4; ++i)
#pragma unroll
    for (int j = 0; j < 4; ++j) acc[i][j] = (f32x4){0.f, 0.f, 0.f, 0.f};

  int c0 = wave * 2, c1 = wave * 2 + 1;
  int sr0 = c0 * 16 + (lane >> 2), sr1 = c1 * 16 + (lane >> 2);
  int sc = (lane & 3) * 8;
  const u16* Ag0 = A + (size_t)(m0 + sr0) * lda + sc;
  const u16* Ag1 = A + (size_t)(m0 + sr1) * lda + sc;
  const u16* Bg0 = Bt + (size_t)(n0 + sr0) * ldb + sc;
  const u16* Bg1 = Bt + (size_t)(n0 + sr1) * ldb + sc;
  u16* lA0 = &As[c0 * 512];
  u16* lA1 = &As[c1 * 512];
  u16* lB0 = &Bs[c0 * 512];
  u16* lB1 = &Bs[c1 * 512];

  int lrow = lane & 15, loct = lane >> 4;
  const int arow0 = (wr * 64 + lrow) * 32 + loct * 8;
  const int brow0 = (wc * 64 + lrow) * 32 + loct * 8;

  for (int k0 = 0; k0 < K; k0 += 32) {
    GLOAD16(Ag0 + k0, lA0);
    GLOAD16(Ag1 + k0, lA1);
    GLOAD16(Bg0 + k0, lB0);
    GLOAD16(Bg1 + k0, lB1);
    __syncthreads();
    bf16x8 af[4], bfr[4];
#pragma unroll
    for (int mf = 0; mf < 4; ++mf)
      af[mf] = *(const bf16x8*)&As[arow0 + mf * 16 * 32];
#pragma unroll
    for (int nf = 0; nf < 4; ++nf)
      bfr[nf] = *(const bf16x8*)&Bs[brow0 + nf * 16 * 32];
#pragma unroll
    for (int mf = 0; mf < 4; ++mf)
#pragma unroll
      for (int nf = 0; nf < 4; ++nf)
        acc[mf][nf] = __builtin_amdgcn_mfma_f32_16x16x32_bf16(
            af[mf], bfr[nf], acc[mf][nf], 0, 0, 0);
    __syncthreads();
  }

  int lq = lane >> 4;
#pragma unroll
  for (int mf = 0; mf < 4; ++mf) {
#pragma unroll
    for (int nf = 0; nf < 4; ++nf) {
      int n = n0 + wc * 64 + nf * 16 + lrow;
      if (n < N) {
        float bv = bias ? bias[n] : 0.f;
#pragma unroll
        for (int j = 0; j < 4; ++j) {
          int m = m0 + wr * 64 + mf * 16 + lq * 4 + j;
          float r = acc[mf][nf][j] + bv;
          if (flags & 1) r += Cf[(size_t)m * ldc + n];
          if (flags & 2) r = fmaxf(r, 0.f);
          if (Cb)
            Cb[(size_t)m * ldc + n] = f2b(r);
          else
            Cf[(size_t)m * ldc + n] = r;
        }
      }
    }
  }
}

// ---------------- MFMA flash attention ---------------------------------------
// 4 waves/block; block = (b,h, 64-row Q tile). KVBLK=64.
// qkv: [B*T][3072] (q | k | v per head), vt: [64 bh][64 d][1024 t]
__global__ __launch_bounds__(256) void fattn_kernel(
    const u16* __restrict__ qkv, const u16* __restrict__ vt,
    u16* __restrict__ o) {
  int t0 = (gridDim.x - 1 - blockIdx.x) * 64;  // heavy tiles first
  int bh = blockIdx.y;
  int b = bh >> 4, hh = bh & 15;
  int tid = threadIdx.x;
  int w = tid >> 6, lane = tid & 63;
  int c = lane & 15, g = lane >> 4;

  __shared__ u16 Ks[64][72];  // [tk][d], pad 72 -> 2-way banks on frag reads
  __shared__ u16 Vs[64][72];  // [d][tk]
  __shared__ u16 Ps[4][16][72];  // wave-private P relayout

  const u16* qbase = qkv + (size_t)(b * T_) * 3072 + hh * 64;
  const u16* kbase = qbase + 1024;
  const u16* vbase = vt + (size_t)bh * 64 * 1024;

  // Q A-frags (hoisted): lane holds Q[row=c][k=g*8+j (+32*kh)], scale folded
  bf16x8 qf[2];
  {
    const u16* qrow = qbase + (size_t)(t0 + w * 16 + c) * 3072 + g * 8;
#pragma unroll
    for (int kh = 0; kh < 2; ++kh) {
      bf16x8 tq = *(const bf16x8*)(qrow + kh * 32);
#pragma unroll
      for (int j = 0; j < 8; ++j) tq[j] = (short)f2b(b2f((u16)tq[j]) * 0.125f);
      qf[kh] = tq;
    }
  }

  float m[4] = {-1e30f, -1e30f, -1e30f, -1e30f};
  float l[4] = {0.f, 0.f, 0.f, 0.f};
  f32x4 acc[4];
#pragma unroll
  for (int ds = 0; ds < 4; ++ds) acc[ds] = (f32x4){0.f, 0.f, 0.f, 0.f};

  int tq0 = t0 + w * 16 + g * 4;  // this lane's row base (regs j=0..3)

  for (int kv0 = 0; kv0 <= t0; kv0 += 64) {
    __syncthreads();  // prev tile fully consumed before overwrite
#pragma unroll
    for (int i = tid; i < 512; i += 256) {
      int r = i >> 3, cc = i & 7;
      *(int4*)&Ks[r][cc * 8] =
          *(const int4*)(kbase + (size_t)(kv0 + r) * 3072 + cc * 8);
      *(int4*)&Vs[r][cc * 8] =
          *(const int4*)(vbase + (size_t)r * 1024 + kv0 + cc * 8);
    }
    __syncthreads();

    // S = Q K^T  (4 col-subtiles x 2 k-steps)
    f32x4 s[4];
#pragma unroll
    for (int ct = 0; ct < 4; ++ct) {
      bf16x8 kf0 = *(const bf16x8*)&Ks[ct * 16 + c][g * 8];
      bf16x8 kf1 = *(const bf16x8*)&Ks[ct * 16 + c][g * 8 + 32];
      s[ct] = (f32x4){0.f, 0.f, 0.f, 0.f};
      s[ct] =
          __builtin_amdgcn_mfma_f32_16x16x32_bf16(qf[0], kf0, s[ct], 0, 0, 0);
      s[ct] =
          __builtin_amdgcn_mfma_f32_16x16x32_bf16(qf[1], kf1, s[ct], 0, 0, 0);
    }
    // causal mask
#pragma unroll
    for (int ct = 0; ct < 4; ++ct) {
      int tk = kv0 + ct * 16 + c;
#pragma unroll
      for (int j = 0; j < 4; ++j)
        if (tk > tq0 + j) s[ct][j] = -1e30f;
    }
    // online softmax (rows live in 16-lane groups)
#pragma unroll
    for (int j = 0; j < 4; ++j) {
      float mt = fmaxf(fmaxf(s[0][j], s[1][j]), fmaxf(s[2][j], s[3][j]));
#pragma unroll
      for (int off = 1; off < 16; off <<= 1)
        mt = fmaxf(mt, __shfl_xor(mt, off));
      float mn = fmaxf(m[j], mt);
      float sc = __expf(m[j] - mn);
      m[j] = mn;
      float rs = 0.f;
#pragma unroll
      for (int ct = 0; ct < 4; ++ct) {
        float p = __expf(s[ct][j] - mn);
        s[ct][j] = p;
        rs += p;
      }
#pragma unroll
      for (int off = 1; off < 16; off <<= 1) rs += __shfl_xor(rs, off);
      l[j] = l[j] * sc + rs;
#pragma unroll
      for (int ds = 0; ds < 4; ++ds) acc[ds][j] *= sc;
    }
    // P -> wave-private LDS (bf16), reload as A-frag
#pragma unroll
    for (int ct = 0; ct < 4; ++ct)
#pragma unroll
      for (int j = 0; j < 4; ++j)
        Ps[w][g * 4 + j][ct * 16 + c] = f2b(s[ct][j]);
    bf16x8 pf0 = *(const bf16x8*)&Ps[w][c][g * 8];
    bf16x8 pf1 = *(const bf16x8*)&Ps[w][c][g * 8 + 32];
    // O += P V  (4 d-subtiles x 2 k-steps)
#pragma unroll
    for (int ds = 0; ds < 4; ++ds) {
      bf16x8 vf0 = *(const bf16x8*)&Vs[ds * 16 + c][g * 8];
      bf16x8 vf1 = *(const bf16x8*)&Vs[ds * 16 + c][g * 8 + 32];
      acc[ds] =
          __builtin_amdgcn_mfma_f32_16x16x32_bf16(pf0, vf0, acc[ds], 0, 0, 0);
      acc[ds] =
          __builtin_amdgcn_mfma_f32_16x16x32_bf16(pf1, vf1, acc[ds], 0, 0, 0);
    }
  }

  float inv[4];
#pragma unroll
  for (int j = 0; j < 4; ++j) inv[j] = 1.0f / l[j];
  u16* orow = o + ((size_t)(b * T_ + tq0)) * E_ + hh * 64;
#pragma unroll
  for (int ds = 0; ds < 4; ++ds)
#pragma unroll
    for (int j = 0; j < 4; ++j)
      orow[(size_t)j * E_ + ds * 16 + c] = f2b(acc[ds][j] * inv[j]);
}

extern "C" void kernel_launch(void* const* d_in, const int* in_sizes, int n_in,
                              void* d_out, int out_size, void* d_ws,
                              size_t ws_size, hipStream_t stream) {
  (void)in_sizes; (void)n_in; (void)out_size; (void)ws_size;
  const int* idx = (const int*)d_in[0];
  const float* tok_emb = (const float*)d_in[1];
  const float* pos_emb = (const float*)d_in[2];
  const float* wq = (const float*)d_in[3];
  const float* wk = (const float*)d_in[4];
  const float* wv = (const float*)d_in[5];
  const float* wo = (const float*)d_in[6];
  const float* bo = (const float*)d_in[7];
  const float* ln1g = (const float*)d_in[8];
  const float* ln1b = (const float*)d_in[9];
  const float* ln2g = (const float*)d_in[10];
  const float* ln2b = (const float*)d_in[11];
  const float* w1 = (const float*)d_in[12];
  const float* b1 = (const float*)d_in[13];
  const float* w2 = (const float*)d_in[14];
  const float* b2 = (const float*)d_in[15];
  const float* lnfg = (const float*)d_in[16];
  const float* lnfb = (const float*)d_in[17];
  float* out = (float*)d_out;
  char* ws = (char*)d_ws;

  // ws layout (bytes); total 125,829,120
  u16* h = (u16*)(ws + 0);             //  8 MB  [4096][1024] bf16
  float* x = (float*)(ws + 8388608);   // 16 MB  [4096][1024] f32
  u16* qkvb = (u16*)(ws + 25165824);   // 24 MB  [4096][3072] bf16
  u16* ob = (u16*)(ws + 50331648);     //  8 MB  [4096][1024] bf16
  u16* ffb = (u16*)(ws + 58720256);    // 32 MB  [4096][4096] bf16
  u16* wqkvT = (u16*)(ws + 92274688);  //  6 MB  [3072][1024] bf16
  u16* woT = (u16*)(ws + 98566144);    //  2 MB  [1024][1024] bf16
  u16* w1T = (u16*)(ws + 100663296);   //  8 MB  [4096][1024] bf16
  u16* w2T = (u16*)(ws + 109051904);   //  8 MB  [1024][4096] bf16
  u16* vtb = (u16*)(ws + 117440512);   //  8 MB  [64][64][1024] bf16
  // tok_bf aliases [x .. w2T) — dead by logits time; does not touch vtb
  u16* tokb = (u16*)(ws + 8388608);    // 103 MB [50304][1024] bf16

  embed_kernel<<<B_ * T_, 256, 0, stream>>>(idx, tok_emb, pos_emb, x);

  for (int l = 0; l < L_; ++l) {
    ln_kernel<<<B_ * T_, 256, 0, stream>>>(x, ln1g + l * E_, ln1b + l * E_, h);
    convQKV_kernel<<<dim3(48, 16), 256, 0, stream>>>(
        wq + (size_t)l * H_ * E_ * HS_, wk + (size_t)l * H_ * E_ * HS_,
        wv + (size_t)l * H_ * E_ * HS_, wqkvT);
    mfma_gemm_kernel<<<dim3(32, 24), 256, 0, stream>>>(
        h, E_, wqkvT, E_, nullptr, nullptr, qkvb, 3072, 3072, E_, 0);
    vtrans_kernel<<<dim3(16, 64), 256, 0, stream>>>(qkvb, vtb);
    fattn_kernel<<<dim3(16, 64), 256, 0, stream>>>(qkvb, vtb, ob);
    convT_kernel<<<dim3(16, 16), 256, 0, stream>>>(
        wo + (size_t)l * E_ * E_, woT, E_, E_);
    mfma_gemm_kernel<<<dim3(32, 8), 256, 0, stream>>>(
        ob, E_, woT, E_, bo + (size_t)l * E_, x, nullptr, E_, E_, E_, 1);
    ln_kernel<<<B_ * T_, 256, 0, stream>>>(x, ln2g + l * E_, ln2b + l * E_, h);
    convT_kernel<<<dim3(64, 16), 256, 0, stream>>>(
        w1 + (size_t)l * E_ * F_DIM, w1T, E_, F_DIM);
    mfma_gemm_kernel<<<dim3(32, 32), 256, 0, stream>>>(
        h, E_, w1T, E_, b1 + (size_t)l * F_DIM, nullptr, ffb, F_DIM, F_DIM,
        E_, 2);
    convT_kernel<<<dim3(16, 64), 256, 0, stream>>>(
        w2 + (size_t)l * F_DIM * E_, w2T, F_DIM, E_);
    mfma_gemm_kernel<<<dim3(32, 8), 256, 0, stream>>>(
        ffb, F_DIM, w2T, F_DIM, b2 + (size_t)l * E_, x, nullptr, E_, E_,
        F_DIM, 1);
  }

  ln_kernel<<<B_ * T_, 256, 0, stream>>>(x, lnfg, lnfb, h);
  convTok_kernel<<<VP_, 256, 0, stream>>>(tok_emb, tokb);
  mfma_gemm_kernel<<<dim3(32, VP_ / 128), 256, 0, stream>>>(
      h, E_, tokb, E_, nullptr, out, nullptr, V_, V_, E_, 0);
}

// Round 4
// 3324.172 us; speedup vs baseline: 10.5531x; 1.0952x over previous
//
#include <hip/hip_runtime.h>
#include <cstdint>

#define B_ 4
#define T_ 1024
#define E_ 1024
#define H_ 16
#define HS_ 64
#define L_ 8
#define F_DIM 4096
#define V_ 50257
#define VP2_ 50432  // V padded to multiple of 256

typedef __attribute__((ext_vector_type(8))) short bf16x8;
typedef __attribute__((ext_vector_type(4))) float f32x4;
typedef unsigned short u16;

__device__ inline float b2f(u16 u) {
  unsigned int v = ((unsigned int)u) << 16;
  return __builtin_bit_cast(float, v);
}
__device__ inline u16 f2b(float f) {
  unsigned int u = __builtin_bit_cast(unsigned int, f);
  unsigned int r = (u + 0x7FFFu + ((u >> 16) & 1u)) >> 16;
  return (u16)r;
}

__device__ inline float wave_sum(float v) {
#pragma unroll
  for (int off = 32; off > 0; off >>= 1) v += __shfl_down(v, off);
  return v;
}

#define GLOAD16(gp, lp)                                                        \
  __builtin_amdgcn_global_load_lds(                                            \
      (const __attribute__((address_space(1))) unsigned int*)(gp),             \
      (__attribute__((address_space(3))) unsigned int*)(lp), 16, 0, 0)

// ---------------- embed ------------------------------------------------------
__global__ __launch_bounds__(256) void embed_kernel(
    const int* __restrict__ idx, const float* __restrict__ tok,
    const float* __restrict__ pos, float* __restrict__ x) {
  int bt = blockIdx.x;
  int t = bt & (T_ - 1);
  int tid = threadIdx.x;
  int tokid = idx[bt];
  float4 a = reinterpret_cast<const float4*>(tok + (size_t)tokid * E_)[tid];
  float4 p = reinterpret_cast<const float4*>(pos + (size_t)t * E_)[tid];
  float4 r = make_float4(a.x + p.x, a.y + p.y, a.z + p.z, a.w + p.w);
  reinterpret_cast<float4*>(x + (size_t)bt * E_)[tid] = r;
}

// ---------------- layernorm fp32 -> bf16 -------------------------------------
__global__ __launch_bounds__(256) void ln_kernel(
    const float* __restrict__ in, const float* __restrict__ g,
    const float* __restrict__ b, u16* __restrict__ out) {
  int row = blockIdx.x;
  int tid = threadIdx.x;
  const float* xr = in + (size_t)row * E_;
  float4 v = reinterpret_cast<const float4*>(xr)[tid];
  float s = v.x + v.y + v.z + v.w;
  float q = v.x * v.x + v.y * v.y + v.z * v.z + v.w * v.w;
  s = wave_sum(s);
  q = wave_sum(q);
  __shared__ float ls[4], lq[4];
  int wid = tid >> 6;
  if ((tid & 63) == 0) { ls[wid] = s; lq[wid] = q; }
  __syncthreads();
  float st = ls[0] + ls[1] + ls[2] + ls[3];
  float qt = lq[0] + lq[1] + lq[2] + lq[3];
  float mu = st * (1.0f / E_);
  float var = qt * (1.0f / E_) - mu * mu;
  float inv = rsqrtf(var + 1e-5f);
  float4 gg = reinterpret_cast<const float4*>(g)[tid];
  float4 bb = reinterpret_cast<const float4*>(b)[tid];
  ushort4 o4;
  o4.x = f2b((v.x - mu) * inv * gg.x + bb.x);
  o4.y = f2b((v.y - mu) * inv * gg.y + bb.y);
  o4.z = f2b((v.z - mu) * inv * gg.z + bb.z);
  o4.w = f2b((v.w - mu) * inv * gg.w + bb.w);
  reinterpret_cast<ushort4*>(out + (size_t)row * E_)[tid] = o4;
}

// ------------- transpose-convert: out[n][k] bf16 <- in[k][n] fp32 ------------
__global__ __launch_bounds__(256) void convT_kernel(
    const float* __restrict__ in, u16* __restrict__ out, int K, int N) {
  __shared__ float tile[64][65];
  int n0 = blockIdx.x * 64, k0 = blockIdx.y * 64;
  int tx = threadIdx.x & 63, ty = threadIdx.x >> 6;
#pragma unroll
  for (int r = 0; r < 64; r += 4)
    tile[r + ty][tx] = in[(size_t)(k0 + r + ty) * N + n0 + tx];
  __syncthreads();
#pragma unroll
  for (int r = 0; r < 64; r += 4)
    out[(size_t)(n0 + r + ty) * K + k0 + tx] = f2b(tile[tx][r + ty]);
}

// --- QKV weight gather: out[(src*1024 + h*64 + d)][e] <- w_src[h][e][d] ------
__global__ __launch_bounds__(256) void convQKV_kernel(
    const float* __restrict__ wq, const float* __restrict__ wk,
    const float* __restrict__ wv, u16* __restrict__ out) {
  int src = blockIdx.x >> 4, hh = blockIdx.x & 15, e0 = blockIdx.y * 64;
  const float* w =
      (src == 0 ? wq : (src == 1 ? wk : wv)) + (size_t)hh * E_ * HS_;
  __shared__ float tile[64][65];
  int tx = threadIdx.x & 63, ty = threadIdx.x >> 6;
#pragma unroll
  for (int r = 0; r < 64; r += 4)
    tile[r + ty][tx] = w[(size_t)(e0 + r + ty) * HS_ + tx];
  __syncthreads();
  size_t nb = (size_t)src * 1024 + hh * 64;
#pragma unroll
  for (int r = 0; r < 64; r += 4)
    out[(nb + r + ty) * E_ + e0 + tx] = f2b(tile[tx][r + ty]);
}

// ---------------- tok_emb straight convert with zero-pad rows ----------------
__global__ __launch_bounds__(256) void convTok_kernel(
    const float* __restrict__ tok, u16* __restrict__ out) {
  int row = blockIdx.x;
  int tid = threadIdx.x;
  ushort4 o4;
  if (row < V_) {
    float4 v = reinterpret_cast<const float4*>(tok + (size_t)row * E_)[tid];
    o4.x = f2b(v.x); o4.y = f2b(v.y); o4.z = f2b(v.z); o4.w = f2b(v.w);
  } else {
    o4 = make_ushort4(0, 0, 0, 0);
  }
  reinterpret_cast<ushort4*>(out + (size_t)row * E_)[tid] = o4;
}

// -------- V transpose: vt[bh][d][t] <- qkv[b*T+t][2048 + h*64 + d] -----------
__global__ __launch_bounds__(256) void vtrans_kernel(
    const u16* __restrict__ qkv, u16* __restrict__ vt) {
  int t0 = blockIdx.x * 64;
  int bh = blockIdx.y;
  int b = bh >> 4, hh = bh & 15;
  __shared__ unsigned int tile[64][65];
  int tx = threadIdx.x & 63, ty = threadIdx.x >> 6;
  const u16* src = qkv + ((size_t)(b * T_ + t0)) * 3072 + 2048 + hh * 64;
#pragma unroll
  for (int r = 0; r < 64; r += 4)
    tile[r + ty][tx] = src[(size_t)(r + ty) * 3072 + tx];
  __syncthreads();
  u16* dst = vt + ((size_t)bh * 64) * 1024 + t0;
#pragma unroll
  for (int r = 0; r < 64; r += 4)
    dst[(size_t)(r + ty) * 1024 + tx] = (u16)tile[tx][r + ty];
}

// ======== 256x256 8-phase MFMA GEMM (T1+T2+T3+T4+T5), BK=64, 8 waves =========
// C[m,n] = sum_k A[m][k] * Bt[n][k]; requires M%256==0, N'%256==0 (padded B),
// K%64==0, grid (M/256)*(N'/256) with nwg%8==0.  flags: 2 = relu.
// Cb!=null -> bf16 out, else fp32 to Cf.  n<N guard on write.
__global__ __launch_bounds__(512) void gemm8p_kernel(
    const u16* __restrict__ A, int lda, const u16* __restrict__ Bt, int ldb,
    const float* __restrict__ bias, float* __restrict__ Cf,
    u16* __restrict__ Cb, int ldc, int N, int K, int gn, int flags) {
  __shared__ u16 As[2][256 * 64];
  __shared__ u16 Bs[2][256 * 64];

  // XCD-aware bijective block swizzle (nwg % 8 == 0 guaranteed by launcher)
  int nwg = gridDim.x;
  int q8 = nwg >> 3;
  int bid = blockIdx.x;
  int wg = (bid & 7) * q8 + (bid >> 3);
  int m0 = (wg / gn) * 256, n0 = (wg % gn) * 256;

  int tid = threadIdx.x;
  int w = tid >> 6, lane = tid & 63;
  int wr = w >> 2, wc = w & 3;  // 2(M) x 4(N) wave grid; wave owns 128x64
  int l15 = lane & 15, lg = lane >> 4;
  int swzr = (l15 & 7) << 3;  // frag-read swizzle (u16 units)

  // staging constants: linear LDS dest, inverse-swizzled global source (m173)
  int l8 = lane >> 3;
  int swz_e = ((lane & 7) ^ l8) << 3;  // u16 offset within 64-elem row
  int wq = w & 3, wh = w >> 2;
  // A pass q rows: wh*128 + q*32 + wq*8 + l8 ; B pass q rows: (w>>1)*64+q*16+(w&1)*8+l8
  const u16* aSrc[4];
  const u16* bSrc[4];
#pragma unroll
  for (int qq = 0; qq < 4; ++qq) {
    aSrc[qq] = A + (size_t)(m0 + wh * 128 + qq * 32 + wq * 8 + l8) * lda;
    bSrc[qq] = Bt + (size_t)(n0 + (w >> 1) * 64 + qq * 16 + (w & 1) * 8 + l8) * ldb;
  }

#define STAGE_A(qq, tt, bb)                                                    \
  GLOAD16(aSrc[qq] + (size_t)(tt) * 64 + swz_e,                                \
          &As[bb][(wh * 128 + (qq) * 32 + wq * 8) * 64])
#define STAGE_B(qq, tt, bb)                                                    \
  GLOAD16(bSrc[qq] + (size_t)(tt) * 64 + swz_e,                                \
          &Bs[bb][((w >> 1) * 64 + (qq) * 16 + (w & 1) * 8) * 64])
#define LDA_OFF(mf, ks) \
  (((wr * 128 + (mf) * 16 + l15) * 64) + ((((ks) * 32) + lg * 8) ^ swzr))
#define LDB_OFF(nf, ks) \
  (((wc * 64 + (nf) * 16 + l15) * 64) + ((((ks) * 32) + lg * 8) ^ swzr))
#define WAITV(n) asm volatile("s_waitcnt vmcnt(" #n ")" ::: "memory")

  f32x4 acc[8][4];
#pragma unroll
  for (int i = 0; i < 8; ++i)
#pragma unroll
    for (int j = 0; j < 4; ++j) acc[i][j] = (f32x4){0.f, 0.f, 0.f, 0.f};

  // prologue: stage tile 0 (order: B0..B3, A0..A3), wait B+Aq0 landed
  STAGE_B(0, 0, 0); STAGE_B(1, 0, 0); STAGE_B(2, 0, 0); STAGE_B(3, 0, 0);
  STAGE_A(0, 0, 0); STAGE_A(1, 0, 0); STAGE_A(2, 0, 0); STAGE_A(3, 0, 0);
  WAITV(3);
  __builtin_amdgcn_sched_barrier(0);
  __builtin_amdgcn_s_barrier();
  __builtin_amdgcn_sched_barrier(0);

  int NT = K >> 6;
  bf16x8 bfrag[4][2];
  for (int t = 0; t < NT; ++t) {
    int cur = t & 1, nxt = cur ^ 1;
    bool pf = (t + 1 < NT);
    int t1 = t + 1;
#pragma unroll
    for (int p = 0; p < 4; ++p) {
      // --- ds-load register subtile for this phase ---
      bf16x8 a0k0 = *(const bf16x8*)&As[cur][LDA_OFF(2 * p + 0, 0)];
      bf16x8 a0k1 = *(const bf16x8*)&As[cur][LDA_OFF(2 * p + 0, 1)];
      bf16x8 a1k0 = *(const bf16x8*)&As[cur][LDA_OFF(2 * p + 1, 0)];
      bf16x8 a1k1 = *(const bf16x8*)&As[cur][LDA_OFF(2 * p + 1, 1)];
      if (p == 0) {
#pragma unroll
        for (int nf = 0; nf < 4; ++nf) {
          bfrag[nf][0] = *(const bf16x8*)&Bs[cur][LDB_OFF(nf, 0)];
          bfrag[nf][1] = *(const bf16x8*)&Bs[cur][LDB_OFF(nf, 1)];
        }
      }
      // --- issue next-tile prefetch (2 gloads/phase) ---
      if (pf) {
        if (p == 0) { STAGE_B(0, t1, nxt); STAGE_B(1, t1, nxt); }
        else if (p == 1) { STAGE_B(2, t1, nxt); STAGE_B(3, t1, nxt); }
        else if (p == 2) { STAGE_A(0, t1, nxt); STAGE_A(1, t1, nxt); }
        else { STAGE_A(2, t1, nxt); STAGE_A(3, t1, nxt); }
      }
      __builtin_amdgcn_s_barrier();
      asm volatile("s_waitcnt lgkmcnt(0)" ::: "memory");
      __builtin_amdgcn_sched_barrier(0);  // rule #18: pin MFMA below the wait
      __builtin_amdgcn_s_setprio(1);
#pragma unroll
      for (int nf = 0; nf < 4; ++nf) {
        acc[2 * p + 0][nf] = __builtin_amdgcn_mfma_f32_16x16x32_bf16(
            a0k0, bfrag[nf][0], acc[2 * p + 0][nf], 0, 0, 0);
        acc[2 * p + 0][nf] = __builtin_amdgcn_mfma_f32_16x16x32_bf16(
            a0k1, bfrag[nf][1], acc[2 * p + 0][nf], 0, 0, 0);
        acc[2 * p + 1][nf] = __builtin_amdgcn_mfma_f32_16x16x32_bf16(
            a1k0, bfrag[nf][0], acc[2 * p + 1][nf], 0, 0, 0);
        acc[2 * p + 1][nf] = __builtin_amdgcn_mfma_f32_16x16x32_bf16(
            a1k1, bfrag[nf][1], acc[2 * p + 1][nf], 0, 0, 0);
      }
      __builtin_amdgcn_s_setprio(0);
      // --- counted vmcnt for NEXT phase's data (never 0 in steady state) ---
      if (pf) {
        if (p == 0) WAITV(4);
        else if (p == 1) WAITV(5);
        else if (p == 2) WAITV(6);
        else WAITV(3);
      } else {
        if (p == 0) WAITV(2);
        else if (p == 1) WAITV(1);
        else WAITV(0);
      }
      __builtin_amdgcn_sched_barrier(0);
      __builtin_amdgcn_s_barrier();
      __builtin_amdgcn_sched_barrier(0);
    }
  }

  // epilogue
#pragma unroll
  for (int mf = 0; mf < 8; ++mf) {
#pragma unroll
    for (int nf = 0; nf < 4; ++nf) {
      int n = n0 + wc * 64 + nf * 16 + l15;
      if (n < N) {
        float bv = bias ? bias[n] : 0.f;
#pragma unroll
        for (int j = 0; j < 4; ++j) {
          int m = m0 + wr * 128 + mf * 16 + lg * 4 + j;
          float r = acc[mf][nf][j] + bv;
          if (flags & 2) r = fmaxf(r, 0.f);
          if (Cb)
            Cb[(size_t)m * ldc + n] = f2b(r);
          else
            Cf[(size_t)m * ldc + n] = r;
        }
      }
    }
  }
#undef STAGE_A
#undef STAGE_B
#undef LDA_OFF
#undef LDB_OFF
#undef WAITV
}

// ---------------- m97-structure 128x128 GEMM (kept for N=1024 shapes) --------
__global__ __launch_bounds__(256) void mfma_gemm_kernel(
    const u16* __restrict__ A, int lda, const u16* __restrict__ Bt, int ldb,
    const float* __restrict__ bias, float* __restrict__ Cf,
    u16* __restrict__ Cb, int ldc, int N, int K, int flags) {
  __shared__ u16 As[128 * 32];
  __shared__ u16 Bs[128 * 32];
  int m0 = blockIdx.x * 128, n0 = blockIdx.y * 128;
  int tid = threadIdx.x;
  int wave = tid >> 6, lane = tid & 63;
  int wr = wave >> 1, wc = wave & 1;

  f32x4 acc[4][4];
#pragma unroll
  for (int i = 0; i < 4; ++i)
#pragma unroll
    for (int j = 0; j < 4; ++j) acc[i][j] = (f32x4){0.f, 0.f, 0.f, 0.f};

  int c0 = wave * 2, c1 = wave * 2 + 1;
  int sr0 = c0 * 16 + (lane >> 2), sr1 = c1 * 16 + (lane >> 2);
  int sc = (lane & 3) * 8;
  const u16* Ag0 = A + (size_t)(m0 + sr0) * lda + sc;
  const u16* Ag1 = A + (size_t)(m0 + sr1) * lda + sc;
  const u16* Bg0 = Bt + (size_t)(n0 + sr0) * ldb + sc;
  const u16* Bg1 = Bt + (size_t)(n0 + sr1) * ldb + sc;
  u16* lA0 = &As[c0 * 512];
  u16* lA1 = &As[c1 * 512];
  u16* lB0 = &Bs[c0 * 512];
  u16* lB1 = &Bs[c1 * 512];

  int lrow = lane & 15, loct = lane >> 4;
  const int arow0 = (wr * 64 + lrow) * 32 + loct * 8;
  const int brow0 = (wc * 64 + lrow) * 32 + loct * 8;

  for (int k0 = 0; k0 < K; k0 += 32) {
    GLOAD16(Ag0 + k0, lA0);
    GLOAD16(Ag1 + k0, lA1);
    GLOAD16(Bg0 + k0, lB0);
    GLOAD16(Bg1 + k0, lB1);
    __syncthreads();
    bf16x8 af[4], bfr[4];
#pragma unroll
    for (int mf = 0; mf < 4; ++mf)
      af[mf] = *(const bf16x8*)&As[arow0 + mf * 16 * 32];
#pragma unroll
    for (int nf = 0; nf < 4; ++nf)
      bfr[nf] = *(const bf16x8*)&Bs[brow0 + nf * 16 * 32];
#pragma unroll
    for (int mf = 0; mf < 4; ++mf)
#pragma unroll
      for (int nf = 0; nf < 4; ++nf)
        acc[mf][nf] = __builtin_amdgcn_mfma_f32_16x16x32_bf16(
            af[mf], bfr[nf], acc[mf][nf], 0, 0, 0);
    __syncthreads();
  }

  int lq = lane >> 4;
#pragma unroll
  for (int mf = 0; mf < 4; ++mf) {
#pragma unroll
    for (int nf = 0; nf < 4; ++nf) {
      int n = n0 + wc * 64 + nf * 16 + lrow;
      if (n < N) {
        float bv = bias ? bias[n] : 0.f;
#pragma unroll
        for (int j = 0; j < 4; ++j) {
          int m = m0 + wr * 64 + mf * 16 + lq * 4 + j;
          float r = acc[mf][nf][j] + bv;
          if (flags & 1) r += Cf[(size_t)m * ldc + n];
          if (flags & 2) r = fmaxf(r, 0.f);
          if (Cb)
            Cb[(size_t)m * ldc + n] = f2b(r);
          else
            Cf[(size_t)m * ldc + n] = r;
        }
      }
    }
  }
}

// ---------------- MFMA flash attention (unchanged from R3) -------------------
__global__ __launch_bounds__(256) void fattn_kernel(
    const u16* __restrict__ qkv, const u16* __restrict__ vt,
    u16* __restrict__ o) {
  int t0 = (gridDim.x - 1 - blockIdx.x) * 64;
  int bh = blockIdx.y;
  int b = bh >> 4, hh = bh & 15;
  int tid = threadIdx.x;
  int w = tid >> 6, lane = tid & 63;
  int c = lane & 15, g = lane >> 4;

  __shared__ u16 Ks[64][72];
  __shared__ u16 Vs[64][72];
  __shared__ u16 Ps[4][16][72];

  const u16* qbase = qkv + (size_t)(b * T_) * 3072 + hh * 64;
  const u16* kbase = qbase + 1024;
  const u16* vbase = vt + (size_t)bh * 64 * 1024;

  bf16x8 qf[2];
  {
    const u16* qrow = qbase + (size_t)(t0 + w * 16 + c) * 3072 + g * 8;
#pragma unroll
    for (int kh = 0; kh < 2; ++kh) {
      bf16x8 tq = *(const bf16x8*)(qrow + kh * 32);
#pragma unroll
      for (int j = 0; j < 8; ++j) tq[j] = (short)f2b(b2f((u16)tq[j]) * 0.125f);
      qf[kh] = tq;
    }
  }

  float m[4] = {-1e30f, -1e30f, -1e30f, -1e30f};
  float l[4] = {0.f, 0.f, 0.f, 0.f};
  f32x4 acc[4];
#pragma unroll
  for (int ds = 0; ds < 4; ++ds) acc[ds] = (f32x4){0.f, 0.f, 0.f, 0.f};

  int tq0 = t0 + w * 16 + g * 4;

  for (int kv0 = 0; kv0 <= t0; kv0 += 64) {
    __syncthreads();
#pragma unroll
    for (int i = tid; i < 512; i += 256) {
      int r = i >> 3, cc = i & 7;
      *(int4*)&Ks[r][cc * 8] =
          *(const int4*)(kbase + (size_t)(kv0 + r) * 3072 + cc * 8);
      *(int4*)&Vs[r][cc * 8] =
          *(const int4*)(vbase + (size_t)r * 1024 + kv0 + cc * 8);
    }
    __syncthreads();

    f32x4 s[4];
#pragma unroll
    for (int ct = 0; ct < 4; ++ct) {
      bf16x8 kf0 = *(const bf16x8*)&Ks[ct * 16 + c][g * 8];
      bf16x8 kf1 = *(const bf16x8*)&Ks[ct * 16 + c][g * 8 + 32];
      s[ct] = (f32x4){0.f, 0.f, 0.f, 0.f};
      s[ct] =
          __builtin_amdgcn_mfma_f32_16x16x32_bf16(qf[0], kf0, s[ct], 0, 0, 0);
      s[ct] =
          __builtin_amdgcn_mfma_f32_16x16x32_bf16(qf[1], kf1, s[ct], 0, 0, 0);
    }
#pragma unroll
    for (int ct = 0; ct < 4; ++ct) {
      int tk = kv0 + ct * 16 + c;
#pragma unroll
      for (int j = 0; j < 4; ++j)
        if (tk > tq0 + j) s[ct][j] = -1e30f;
    }
#pragma unroll
    for (int j = 0; j < 4; ++j) {
      float mt = fmaxf(fmaxf(s[0][j], s[1][j]), fmaxf(s[2][j], s[3][j]));
#pragma unroll
      for (int off = 1; off < 16; off <<= 1)
        mt = fmaxf(mt, __shfl_xor(mt, off));
      float mn = fmaxf(m[j], mt);
      float sc = __expf(m[j] - mn);
      m[j] = mn;
      float rs = 0.f;
#pragma unroll
      for (int ct = 0; ct < 4; ++ct) {
        float p = __expf(s[ct][j] - mn);
        s[ct][j] = p;
        rs += p;
      }
#pragma unroll
      for (int off = 1; off < 16; off <<= 1) rs += __shfl_xor(rs, off);
      l[j] = l[j] * sc + rs;
#pragma unroll
      for (int ds = 0; ds < 4; ++ds) acc[ds][j] *= sc;
    }
#pragma unroll
    for (int ct = 0; ct < 4; ++ct)
#pragma unroll
      for (int j = 0; j < 4; ++j)
        Ps[w][g * 4 + j][ct * 16 + c] = f2b(s[ct][j]);
    bf16x8 pf0 = *(const bf16x8*)&Ps[w][c][g * 8];
    bf16x8 pf1 = *(const bf16x8*)&Ps[w][c][g * 8 + 32];
#pragma unroll
    for (int ds = 0; ds < 4; ++ds) {
      bf16x8 vf0 = *(const bf16x8*)&Vs[ds * 16 + c][g * 8];
      bf16x8 vf1 = *(const bf16x8*)&Vs[ds * 16 + c][g * 8 + 32];
      acc[ds] =
          __builtin_amdgcn_mfma_f32_16x16x32_bf16(pf0, vf0, acc[ds], 0, 0, 0);
      acc[ds] =
          __builtin_amdgcn_mfma_f32_16x16x32_bf16(pf1, vf1, acc[ds], 0, 0, 0);
    }
  }

  float inv[4];
#pragma unroll
  for (int j = 0; j < 4; ++j) inv[j] = 1.0f / l[j];
  u16* orow = o + ((size_t)(b * T_ + tq0)) * E_ + hh * 64;
#pragma unroll
  for (int ds = 0; ds < 4; ++ds)
#pragma unroll
    for (int j = 0; j < 4; ++j)
      orow[(size_t)j * E_ + ds * 16 + c] = f2b(acc[ds][j] * inv[j]);
}

extern "C" void kernel_launch(void* const* d_in, const int* in_sizes, int n_in,
                              void* d_out, int out_size, void* d_ws,
                              size_t ws_size, hipStream_t stream) {
  (void)in_sizes; (void)n_in; (void)out_size; (void)ws_size;
  const int* idx = (const int*)d_in[0];
  const float* tok_emb = (const float*)d_in[1];
  const float* pos_emb = (const float*)d_in[2];
  const float* wq = (const float*)d_in[3];
  const float* wk = (const float*)d_in[4];
  const float* wv = (const float*)d_in[5];
  const float* wo = (const float*)d_in[6];
  const float* bo = (const float*)d_in[7];
  const float* ln1g = (const float*)d_in[8];
  const float* ln1b = (const float*)d_in[9];
  const float* ln2g = (const float*)d_in[10];
  const float* ln2b = (const float*)d_in[11];
  const float* w1 = (const float*)d_in[12];
  const float* b1 = (const float*)d_in[13];
  const float* w2 = (const float*)d_in[14];
  const float* b2 = (const float*)d_in[15];
  const float* lnfg = (const float*)d_in[16];
  const float* lnfb = (const float*)d_in[17];
  float* out = (float*)d_out;
  char* ws = (char*)d_ws;

  // ws layout (bytes)
  u16* h = (u16*)(ws + 0);             //  8 MB  [4096][1024] bf16
  float* x = (float*)(ws + 8388608);   // 16 MB  [4096][1024] f32
  u16* qkvb = (u16*)(ws + 25165824);   // 24 MB  [4096][3072] bf16
  u16* ob = (u16*)(ws + 50331648);     //  8 MB  [4096][1024] bf16
  u16* ffb = (u16*)(ws + 58720256);    // 32 MB  [4096][4096] bf16
  u16* wqkvT = (u16*)(ws + 92274688);  //  6 MB  [3072][1024] bf16
  u16* woT = (u16*)(ws + 98566144);    //  2 MB  [1024][1024] bf16
  u16* w1T = (u16*)(ws + 100663296);   //  8 MB  [4096][1024] bf16
  u16* w2T = (u16*)(ws + 109051904);   //  8 MB  [1024][4096] bf16
  u16* vtb = (u16*)(ws + 117440512);   //  8 MB  [64][64][1024] bf16
  // tok_bf aliases [x .. w2T+) — dead by logits time; does not touch vtb
  u16* tokb = (u16*)(ws + 8388608);    // 103.3 MB [50432][1024] bf16

  embed_kernel<<<B_ * T_, 256, 0, stream>>>(idx, tok_emb, pos_emb, x);

  for (int l = 0; l < L_; ++l) {
    ln_kernel<<<B_ * T_, 256, 0, stream>>>(x, ln1g + l * E_, ln1b + l * E_, h);
    convQKV_kernel<<<dim3(48, 16), 256, 0, stream>>>(
        wq + (size_t)l * H_ * E_ * HS_, wk + (size_t)l * H_ * E_ * HS_,
        wv + (size_t)l * H_ * E_ * HS_, wqkvT);
    // qkv = h @ Wqkv  [4096][3072]: 16 x 12 = 192 blocks (%8==0)
    gemm8p_kernel<<<16 * 12, 512, 0, stream>>>(
        h, E_, wqkvT, E_, nullptr, nullptr, qkvb, 3072, 3072, E_, 12, 0);
    vtrans_kernel<<<dim3(16, 64), 256, 0, stream>>>(qkvb, vtb);
    fattn_kernel<<<dim3(16, 64), 256, 0, stream>>>(qkvb, vtb, ob);
    convT_kernel<<<dim3(16, 16), 256, 0, stream>>>(
        wo + (size_t)l * E_ * E_, woT, E_, E_);
    // x += o @ wo + bo  (N=1024 -> m97 kernel, full CU coverage)
    mfma_gemm_kernel<<<dim3(32, 8), 256, 0, stream>>>(
        ob, E_, woT, E_, bo + (size_t)l * E_, x, nullptr, E_, E_, E_, 1);
    ln_kernel<<<B_ * T_, 256, 0, stream>>>(x, ln2g + l * E_, ln2b + l * E_, h);
    convT_kernel<<<dim3(64, 16), 256, 0, stream>>>(
        w1 + (size_t)l * E_ * F_DIM, w1T, E_, F_DIM);
    // ff = relu(h @ w1 + b1)  [4096][4096]: 16 x 16 = 256 blocks
    gemm8p_kernel<<<16 * 16, 512, 0, stream>>>(
        h, E_, w1T, E_, b1 + (size_t)l * F_DIM, nullptr, ffb, F_DIM, F_DIM,
        E_, 16, 2);
    convT_kernel<<<dim3(16, 64), 256, 0, stream>>>(
        w2 + (size_t)l * F_DIM * E_, w2T, F_DIM, E_);
    // x += ff @ w2 + b2  (N=1024, K=4096 -> m97 kernel)
    mfma_gemm_kernel<<<dim3(32, 8), 256, 0, stream>>>(
        ffb, F_DIM, w2T, F_DIM, b2 + (size_t)l * E_, x, nullptr, E_, E_,
        F_DIM, 1);
  }

  ln_kernel<<<B_ * T_, 256, 0, stream>>>(x, lnfg, lnfb, h);
  convTok_kernel<<<VP2_, 256, 0, stream>>>(tok_emb, tokb);
  // logits = h @ tok_emb^T  [4096][50257]: 16 x 197 = 3152 blocks (%8==0)
  gemm8p_kernel<<<16 * (VP2_ / 256), 512, 0, stream>>>(
      h, E_, tokb, E_, nullptr, out, nullptr, V_, V_, E_, VP2_ / 256, 0);
}